// Round 13
// baseline (408.103 us; speedup 1.0000x reference)
//
#include <hip/hip_runtime.h>
#include <math.h>

#define NS 10000
#define LSEQ 32
#define DDIM 300
#define HDIM 300
#define BB 256
#define NMAX 128
#define MMAX 128
#define EPSR 0.1f
#define SITERS 50
#define KPAD 320
#define NPADW 384

typedef __attribute__((ext_vector_type(8))) short bf16x8;
typedef __attribute__((ext_vector_type(4))) float f32x4;

__device__ __forceinline__ ushort f2bf(float x) {
  union { float f; unsigned u; } c; c.f = x;
  unsigned r = (c.u + 0x7fffu + ((c.u >> 16) & 1u)) >> 16;
  return (ushort)r;
}
__device__ __forceinline__ float bf2f(ushort h) {
  union { unsigned u; float f; } c; c.u = ((unsigned)h) << 16;
  return c.f;
}

// ------- K1: embedding + masked mean pool -> enc hi/lo [NS][KPAD] bf16 -----
__global__ __launch_bounds__(256) void k_embed(const int* __restrict__ data,
                                               const float* __restrict__ emb,
                                               ushort* __restrict__ enchi,
                                               ushort* __restrict__ enclo) {
  __shared__ int ids[LSEQ];
  __shared__ __align__(16) float4 part[3][76];
  int s = blockIdx.x;
  int tid = threadIdx.x;
  if (tid < LSEQ) ids[tid] = data[s * LSEQ + tid];
  __syncthreads();
  int cnt = 0;
#pragma unroll
  for (int t = 0; t < LSEQ; ++t) cnt += (ids[t] != 0) ? 1 : 0;
  int g = tid / 75, d = tid - g * 75;
  const float4* emb4 = (const float4*)emb;
  if (g < 3) {
    float4 acc = make_float4(0.f, 0.f, 0.f, 0.f);
    for (int t = g; t < LSEQ; t += 3) {
      int id = ids[t];
      if (id != 0) {
        float4 e = emb4[(size_t)id * 75 + d];
        acc.x += e.x; acc.y += e.y; acc.z += e.z; acc.w += e.w;
      }
    }
    part[g][d] = acc;
  }
  __syncthreads();
  if (g == 0) {
    float4 a = part[0][d], b = part[1][d], c = part[2][d];
    float inv = 1.f / (float)(cnt > 0 ? cnt : 1);
    float v[4] = {(a.x + b.x + c.x) * inv, (a.y + b.y + c.y) * inv,
                  (a.z + b.z + c.z) * inv, (a.w + b.w + c.w) * inv};
    ushort4 h, l;
    h.x = f2bf(v[0]); l.x = f2bf(v[0] - bf2f(h.x));
    h.y = f2bf(v[1]); l.y = f2bf(v[1] - bf2f(h.y));
    h.z = f2bf(v[2]); l.z = f2bf(v[2] - bf2f(h.z));
    h.w = f2bf(v[3]); l.w = f2bf(v[3] - bf2f(h.w));
    *(ushort4*)&enchi[(size_t)s * KPAD + d * 4] = h;
    *(ushort4*)&enclo[(size_t)s * KPAD + d * 4] = l;
  } else if (g == 1 && d < 5) {
    ushort4 z; z.x = z.y = z.z = z.w = 0;
    *(ushort4*)&enchi[(size_t)s * KPAD + 300 + d * 4] = z;
    *(ushort4*)&enclo[(size_t)s * KPAD + 300 + d * 4] = z;
  }
}

// ------- K2: all weight converts in one dispatch ---------------------------
__global__ __launch_bounds__(256) void k_cvt_all(
    const float* __restrict__ W1, const float* __restrict__ W2,
    const float* __restrict__ Wc, ushort* __restrict__ W1hi,
    ushort* __restrict__ W1lo, ushort* __restrict__ W2hi,
    ushort* __restrict__ W2lo, ushort* __restrict__ Wchi,
    ushort* __restrict__ Wclo) {
  int i = blockIdx.x * 256 + threadIdx.x;
  const int SA = NPADW * KPAD;
  const int SC = 640 * KPAD;
  float v = 0.f;
  ushort *ph, *pl;
  int idx;
  if (i < SA) {
    idx = i;
    int n = idx / KPAD, k = idx - n * KPAD;
    if (n < HDIM && k < DDIM) v = W1[(size_t)k * HDIM + n];
    ph = W1hi; pl = W1lo;
  } else if (i < 2 * SA) {
    idx = i - SA;
    int n = idx / KPAD, k = idx - n * KPAD;
    if (n < HDIM && k < HDIM) v = W2[(size_t)k * HDIM + n];
    ph = W2hi; pl = W2lo;
  } else if (i < 2 * SA + SC) {
    idx = i - 2 * SA;
    int n = idx / KPAD, k = idx - n * KPAD;
    if (k < HDIM && n < 2 * HDIM)
      v = (n < HDIM) ? Wc[(size_t)k * HDIM + n]
                     : Wc[(size_t)(HDIM + k) * HDIM + (n - HDIM)];
    ph = Wchi; pl = Wclo;
  } else {
    return;
  }
  ushort h = f2bf(v);
  ph[idx] = h;
  pl[idx] = f2bf(v - bf2f(h));
}

// ------- K3: MFMA GEMM, hi/lo 3-term, 64x128 tile, wave = 32x64 ------------
// Cf: f32 out, first cf_n cols. Chi/Clo: bf16 hi/lo planes [M][KPAD] holding
// cols [chi_off, chi_off+KPAD) (cols >= N zeroed).
__global__ __launch_bounds__(256) void k_gemm_mfma(
    const ushort* __restrict__ Ahi, const ushort* __restrict__ Alo,
    const ushort* __restrict__ BhiT, const ushort* __restrict__ BloT,
    const float* __restrict__ bias, int M, int N, int relu,
    float* __restrict__ Cf, int cf_n, ushort* __restrict__ Chi,
    ushort* __restrict__ Clo, int chi_off) {
  __shared__ __align__(16) ushort ldsA[2][64][40];
  __shared__ __align__(16) ushort ldsB[2][128][40];
  int tid = threadIdx.x;
  int m0 = blockIdx.x * 64, n0 = blockIdx.y * 128;
  int rowA = tid >> 2, chA = (tid & 3) * 8;
  int rowB = tid >> 1, chB = (tid & 1) * 16;
  bool mok = (m0 + rowA) < M;
  const ushort* pAh = Ahi + (size_t)(m0 + rowA) * KPAD + chA;
  const ushort* pAl = Alo + (size_t)(m0 + rowA) * KPAD + chA;
  const ushort* pBh = BhiT + (size_t)(n0 + rowB) * KPAD + chB;
  const ushort* pBl = BloT + (size_t)(n0 + rowB) * KPAD + chB;
  uint4 rAh, rAl, rBh0, rBh1, rBl0, rBl1;
  uint4 z4; z4.x = z4.y = z4.z = z4.w = 0;
  auto ld = [&](int c) {
    int o = c * 32;
    rAh = mok ? *(const uint4*)(pAh + o) : z4;
    rAl = mok ? *(const uint4*)(pAl + o) : z4;
    rBh0 = *(const uint4*)(pBh + o);
    rBh1 = *(const uint4*)(pBh + o + 8);
    rBl0 = *(const uint4*)(pBl + o);
    rBl1 = *(const uint4*)(pBl + o + 8);
  };
  auto st = [&]() {
    *(uint4*)&ldsA[0][rowA][chA] = rAh;
    *(uint4*)&ldsA[1][rowA][chA] = rAl;
    *(uint4*)&ldsB[0][rowB][chB] = rBh0;
    *(uint4*)&ldsB[0][rowB][chB + 8] = rBh1;
    *(uint4*)&ldsB[1][rowB][chB] = rBl0;
    *(uint4*)&ldsB[1][rowB][chB + 8] = rBl1;
  };
  int w = tid >> 6, lane = tid & 63;
  int q = lane >> 4, l16 = lane & 15;
  int mh = w >> 1, nh = w & 1;
  f32x4 zf = {0.f, 0.f, 0.f, 0.f};
  f32x4 acc[2][4];
#pragma unroll
  for (int s = 0; s < 2; ++s)
#pragma unroll
    for (int t = 0; t < 4; ++t) acc[s][t] = zf;
  ld(0); st(); __syncthreads();
  for (int c = 0; c < 10; ++c) {
    if (c < 9) ld(c + 1);
    bf16x8 ah0 = *(const bf16x8*)&ldsA[0][mh * 32 + l16][q * 8];
    bf16x8 ah1 = *(const bf16x8*)&ldsA[0][mh * 32 + 16 + l16][q * 8];
    bf16x8 al0 = *(const bf16x8*)&ldsA[1][mh * 32 + l16][q * 8];
    bf16x8 al1 = *(const bf16x8*)&ldsA[1][mh * 32 + 16 + l16][q * 8];
#pragma unroll
    for (int t = 0; t < 4; ++t) {
      int brow = nh * 64 + t * 16 + l16;
      bf16x8 bh = *(const bf16x8*)&ldsB[0][brow][q * 8];
      bf16x8 bl = *(const bf16x8*)&ldsB[1][brow][q * 8];
      acc[0][t] = __builtin_amdgcn_mfma_f32_16x16x32_bf16(ah0, bh, acc[0][t], 0, 0, 0);
      acc[0][t] = __builtin_amdgcn_mfma_f32_16x16x32_bf16(ah0, bl, acc[0][t], 0, 0, 0);
      acc[0][t] = __builtin_amdgcn_mfma_f32_16x16x32_bf16(al0, bh, acc[0][t], 0, 0, 0);
      acc[1][t] = __builtin_amdgcn_mfma_f32_16x16x32_bf16(ah1, bh, acc[1][t], 0, 0, 0);
      acc[1][t] = __builtin_amdgcn_mfma_f32_16x16x32_bf16(ah1, bl, acc[1][t], 0, 0, 0);
      acc[1][t] = __builtin_amdgcn_mfma_f32_16x16x32_bf16(al1, bh, acc[1][t], 0, 0, 0);
    }
    __syncthreads();
    if (c < 9) st();
    __syncthreads();
  }
#pragma unroll
  for (int t = 0; t < 4; ++t) {
    int n = n0 + nh * 64 + t * 16 + l16;
    bool nin = n < N;
    float bz = (bias && nin) ? bias[n] : 0.f;
#pragma unroll
    for (int s = 0; s < 2; ++s) {
#pragma unroll
      for (int r = 0; r < 4; ++r) {
        int m = m0 + mh * 32 + s * 16 + q * 4 + r;
        if (m >= M) continue;
        float v = acc[s][t][r] + bz;
        if (relu) v = v > 0.f ? v : 0.f;
        if (Cf && n < cf_n) Cf[(size_t)m * cf_n + n] = v;
        if (Chi) {
          int nc = n - chi_off;
          if (nc >= 0 && nc < KPAD) {
            ushort h = 0, l = 0;
            if (nin) { h = f2bf(v); l = f2bf(v - bf2f(h)); }
            Chi[(size_t)m * KPAD + nc] = h;
            Clo[(size_t)m * KPAD + nc] = l;
          }
        }
      }
    }
  }
}

// --- K4: normalize henc (hi/lo) -> hn hi/lo [NS][KPAD] (unit rows) ---------
__global__ __launch_bounds__(256) void k_norm_split(
    const ushort* __restrict__ hehi, const ushort* __restrict__ helo,
    ushort* __restrict__ hnhi, ushort* __restrict__ hnlo) {
  int s = blockIdx.x * 4 + (threadIdx.x >> 6);
  int lane = threadIdx.x & 63;
  if (s >= NS) return;
  const ushort* ph = hehi + (size_t)s * KPAD;
  const ushort* pl = helo + (size_t)s * KPAD;
  float x[5];
  float ss = 0.f;
#pragma unroll
  for (int q = 0; q < 5; ++q) {
    int d = lane + q * 64;
    x[q] = bf2f(ph[d]) + bf2f(pl[d]);
    ss += x[q] * x[q];
  }
#pragma unroll
  for (int off = 32; off > 0; off >>= 1) ss += __shfl_down(ss, off, 64);
  ss = __shfl(ss, 0, 64);
  float inv = 1.f / (sqrtf(ss) + 1e-8f);
  ushort* qh = hnhi + (size_t)s * KPAD;
  ushort* ql = hnlo + (size_t)s * KPAD;
#pragma unroll
  for (int q = 0; q < 5; ++q) {
    int d = lane + q * 64;
    float v = x[q] * inv;
    ushort h = f2bf(v);
    qh[d] = h;
    ql[d] = f2bf(v - bf2f(h));
  }
}

// --- K5: cost as gathered MFMA GEMM (hn·hn^T) + fused exp, wave = 32x32 ----
__global__ __launch_bounds__(256) void k_cost_mfma(
    const ushort* __restrict__ hnhi, const ushort* __restrict__ hnlo,
    const int* __restrict__ ridx, const int* __restrict__ cidx,
    const int* __restrict__ rlen, const int* __restrict__ clen,
    float* __restrict__ Kmat) {
  int b = blockIdx.z;
  int r0 = blockIdx.x * 64, c0 = blockIdx.y * 64;
  int rl = rlen[b], cl = clen[b];
  float* Kg = Kmat + (size_t)b * NMAX * MMAX;
  int tid = threadIdx.x;
  if (r0 >= rl || c0 >= cl) {
    for (int l = tid; l < 64 * 16; l += 256) {
      int i = l >> 4, j = (l & 15) << 2;
      *(float4*)&Kg[(size_t)(r0 + i) * MMAX + c0 + j] =
          make_float4(0.f, 0.f, 0.f, 0.f);
    }
    return;
  }
  __shared__ int rix[64], cix[64];
  __shared__ __align__(16) ushort lds[4][64][40];  // Rhi,Rlo,Chi,Clo
  if (tid < 64) rix[tid] = ridx[b * NMAX + r0 + tid];
  else if (tid < 128) cix[tid - 64] = cidx[b * MMAX + c0 + tid - 64];
  __syncthreads();
  int row = tid >> 2, ch = tid & 3;
  const ushort* pRh = hnhi + (size_t)rix[row] * KPAD + ch * 8;
  const ushort* pRl = hnlo + (size_t)rix[row] * KPAD + ch * 8;
  const ushort* pCh = hnhi + (size_t)cix[row] * KPAD + ch * 8;
  const ushort* pCl = hnlo + (size_t)cix[row] * KPAD + ch * 8;
  uint4 rRh, rRl, rCh, rCl;
  auto ld = [&](int c) {
    int o = c * 32;
    rRh = *(const uint4*)(pRh + o);
    rRl = *(const uint4*)(pRl + o);
    rCh = *(const uint4*)(pCh + o);
    rCl = *(const uint4*)(pCl + o);
  };
  auto st = [&]() {
    *(uint4*)&lds[0][row][ch * 8] = rRh;
    *(uint4*)&lds[1][row][ch * 8] = rRl;
    *(uint4*)&lds[2][row][ch * 8] = rCh;
    *(uint4*)&lds[3][row][ch * 8] = rCl;
  };
  int w = tid >> 6, lane = tid & 63;
  int q = lane >> 4, l16 = lane & 15;
  int mh = w >> 1, nh = w & 1;
  f32x4 zf = {0.f, 0.f, 0.f, 0.f};
  f32x4 acc[2][2];
#pragma unroll
  for (int s = 0; s < 2; ++s)
#pragma unroll
    for (int t = 0; t < 2; ++t) acc[s][t] = zf;
  ld(0); st(); __syncthreads();
  for (int c = 0; c < 10; ++c) {
    if (c < 9) ld(c + 1);
    bf16x8 ah0 = *(const bf16x8*)&lds[0][mh * 32 + l16][q * 8];
    bf16x8 ah1 = *(const bf16x8*)&lds[0][mh * 32 + 16 + l16][q * 8];
    bf16x8 al0 = *(const bf16x8*)&lds[1][mh * 32 + l16][q * 8];
    bf16x8 al1 = *(const bf16x8*)&lds[1][mh * 32 + 16 + l16][q * 8];
#pragma unroll
    for (int t = 0; t < 2; ++t) {
      int brow = nh * 32 + t * 16 + l16;
      bf16x8 bh = *(const bf16x8*)&lds[2][brow][q * 8];
      bf16x8 bl = *(const bf16x8*)&lds[3][brow][q * 8];
      acc[0][t] = __builtin_amdgcn_mfma_f32_16x16x32_bf16(ah0, bh, acc[0][t], 0, 0, 0);
      acc[0][t] = __builtin_amdgcn_mfma_f32_16x16x32_bf16(ah0, bl, acc[0][t], 0, 0, 0);
      acc[0][t] = __builtin_amdgcn_mfma_f32_16x16x32_bf16(al0, bh, acc[0][t], 0, 0, 0);
      acc[1][t] = __builtin_amdgcn_mfma_f32_16x16x32_bf16(ah1, bh, acc[1][t], 0, 0, 0);
      acc[1][t] = __builtin_amdgcn_mfma_f32_16x16x32_bf16(ah1, bl, acc[1][t], 0, 0, 0);
      acc[1][t] = __builtin_amdgcn_mfma_f32_16x16x32_bf16(al1, bh, acc[1][t], 0, 0, 0);
    }
    __syncthreads();
    if (c < 9) st();
    __syncthreads();
  }
#pragma unroll
  for (int t = 0; t < 2; ++t) {
    int n = c0 + nh * 32 + t * 16 + l16;
#pragma unroll
    for (int s = 0; s < 2; ++s) {
#pragma unroll
      for (int r = 0; r < 4; ++r) {
        int m = r0 + mh * 32 + s * 16 + q * 4 + r;
        float kv = (m < rl && n < cl) ? expf((acc[s][t][r] - 1.f) / EPSR) : 0.f;
        Kg[(size_t)m * MMAX + n] = kv;
      }
    }
  }
}

// --- K6: Sinkhorn (K in VGPRs) + fused P / P^T emission as bf16 hi/lo ------
// Emits Phi/Plo [b][n][k] (P) and PThi/PTlo [b][n][k] (P^T) — both row-major
// so the attend kernel reads a coalesced A-operand for either side.
__global__ __launch_bounds__(512) void k_sinkhorn(
    const float* __restrict__ Kmat, const int* __restrict__ rlen,
    const int* __restrict__ clen, ushort* __restrict__ Phi,
    ushort* __restrict__ Plo, ushort* __restrict__ PThi,
    ushort* __restrict__ PTlo) {
  __shared__ __align__(16) float vq[4][36];
  __shared__ __align__(16) float uq[4][36];
  int b = blockIdx.x;
  int tid = threadIdx.x;
  int n = tid >> 2, q = tid & 3;
  int rl = rlen[b], cl = clen[b];
  const float* Kg = Kmat + (size_t)b * NMAX * MMAX;
  float kr[32], kt[32];
  const float4* Kg4 = (const float4*)(Kg + (size_t)n * MMAX + 32 * q);
#pragma unroll
  for (int t = 0; t < 8; ++t) *(float4*)&kr[4 * t] = Kg4[t];
#pragma unroll
  for (int j = 0; j < 32; ++j) kt[j] = Kg[(size_t)(32 * q + j) * MMAX + n];
  if (tid < 128) vq[tid >> 5][tid & 31] = (tid < cl) ? 1.f : 0.f;
  float av = (n < rl) ? 1.f / (float)rl : 0.f;
  float bv = (n < cl) ? 1.f / (float)cl : 0.f;
  float un = 0.f, vm = 0.f;
  __syncthreads();
  for (int it = 0; it < SITERS; ++it) {
    float s = 0.f;
#pragma unroll
    for (int t = 0; t < 8; ++t) {
      float4 vv = *(const float4*)&vq[q][4 * t];
      s += kr[4 * t + 0] * vv.x + kr[4 * t + 1] * vv.y +
           kr[4 * t + 2] * vv.z + kr[4 * t + 3] * vv.w;
    }
    s += __shfl_xor(s, 1, 64);
    s += __shfl_xor(s, 2, 64);
    un = (n < rl) ? av / s : 0.f;
    if (q == 0) uq[n >> 5][n & 31] = un;
    __syncthreads();
    float s2 = 0.f;
#pragma unroll
    for (int t = 0; t < 8; ++t) {
      float4 uu = *(const float4*)&uq[q][4 * t];
      s2 += kt[4 * t + 0] * uu.x + kt[4 * t + 1] * uu.y +
            kt[4 * t + 2] * uu.z + kt[4 * t + 3] * uu.w;
    }
    s2 += __shfl_xor(s2, 1, 64);
    s2 += __shfl_xor(s2, 2, 64);
    vm = (n < cl) ? bv / s2 : 0.f;
    if (q == 0) vq[n >> 5][n & 31] = vm;
    __syncthreads();
  }
  // ---- fused P = u K v (and P^T) emission, bf16 hi/lo -------------------
  size_t pb = (((size_t)b << 7) + n) * 128 + 32 * q;
#pragma unroll
  for (int t = 0; t < 8; ++t) {
    float4 vv = *(const float4*)&vq[q][4 * t];
    float4 uu = *(const float4*)&uq[q][4 * t];
    float p0 = un * kr[4 * t + 0] * vv.x;
    float p1 = un * kr[4 * t + 1] * vv.y;
    float p2 = un * kr[4 * t + 2] * vv.z;
    float p3 = un * kr[4 * t + 3] * vv.w;
    float w0 = uu.x * kt[4 * t + 0] * vm;
    float w1 = uu.y * kt[4 * t + 1] * vm;
    float w2 = uu.z * kt[4 * t + 2] * vm;
    float w3 = uu.w * kt[4 * t + 3] * vm;
    ushort4 hv, lv, hw, lw;
    hv.x = f2bf(p0); lv.x = f2bf(p0 - bf2f(hv.x));
    hv.y = f2bf(p1); lv.y = f2bf(p1 - bf2f(hv.y));
    hv.z = f2bf(p2); lv.z = f2bf(p2 - bf2f(hv.z));
    hv.w = f2bf(p3); lv.w = f2bf(p3 - bf2f(hv.w));
    hw.x = f2bf(w0); lw.x = f2bf(w0 - bf2f(hw.x));
    hw.y = f2bf(w1); lw.y = f2bf(w1 - bf2f(hw.y));
    hw.z = f2bf(w2); lw.z = f2bf(w2 - bf2f(hw.z));
    hw.w = f2bf(w3); lw.w = f2bf(w3 - bf2f(hw.w));
    *(ushort4*)&Phi[pb + 4 * t] = hv;
    *(ushort4*)&Plo[pb + 4 * t] = lv;
    *(ushort4*)&PThi[pb + 4 * t] = hw;
    *(ushort4*)&PTlo[pb + 4 * t] = lw;
  }
}

// ---- K7: attend+compare via MFMA. Block = (d-tile 64, batch, side). -------
// A = P (side 0) or P^T (side 1), bf16 hi/lo row-major. B = gathered Hcb^T,
// transposed into LDS once per block. 3-term hi/lo MFMA; epilogue adds
// Hc + bc, relu, masked column-sum.
__global__ __launch_bounds__(256) void k_att_mfma(
    const ushort* __restrict__ Phi, const ushort* __restrict__ Plo,
    const ushort* __restrict__ PThi, const ushort* __restrict__ PTlo,
    const float* __restrict__ Hc, const ushort* __restrict__ Hcbhi,
    const ushort* __restrict__ Hcblo, const int* __restrict__ row_idx,
    const int* __restrict__ col_idx, const int* __restrict__ row_len,
    const int* __restrict__ col_len, const float* __restrict__ bc,
    float* __restrict__ cr, float* __restrict__ cc) {
  int b = blockIdx.y;
  int side = blockIdx.z;
  int d0 = blockIdx.x * 64;
  const int* idx_main = side == 0 ? row_idx : col_idx;
  const int* idx_other = side == 0 ? col_idx : row_idx;
  int lm = side == 0 ? row_len[b] : col_len[b];
  int lo = side == 0 ? col_len[b] : row_len[b];
  float* outacc = side == 0 ? cr : cc;
  const ushort* Pbh = (side == 0 ? Phi : PThi) + ((size_t)b << 14);
  const ushort* Pbl = (side == 0 ? Plo : PTlo) + ((size_t)b << 14);
  __shared__ __align__(16) ushort Gh[64][152];  // stride 152: 16B-aligned,
  __shared__ __align__(16) ushort Gl[64][152];  //   ~2-way bank pattern
  __shared__ __align__(16) ushort Ph[64][136];
  __shared__ __align__(16) ushort Pl[64][136];
  __shared__ int iox[NMAX];
  __shared__ int imx[NMAX];
  __shared__ float red[128];
  int tid = threadIdx.x;
  if (tid < 128) iox[tid] = idx_other[b * NMAX + tid];
  else imx[tid - 128] = idx_main[b * NMAX + tid - 128];
  __syncthreads();
  int nkc = (lo + 31) >> 5;  // K chunks of 32 (P zero-padded past lo: exact)
  // ---- stage G^T once: Gh[d][k] = Hcbhi[iox[k]][d0+d] ----
  {
    int k = tid >> 1;
    int dh = (tid & 1) * 32;
    if (k < nkc * 32) {
      const uint4* sh = (const uint4*)(Hcbhi + (size_t)iox[k] * KPAD + d0 + dh);
      const uint4* sl = (const uint4*)(Hcblo + (size_t)iox[k] * KPAD + d0 + dh);
      ushort hs[32], ls[32];
#pragma unroll
      for (int i = 0; i < 4; ++i) {
        *(uint4*)&hs[8 * i] = sh[i];
        *(uint4*)&ls[8 * i] = sl[i];
      }
#pragma unroll
      for (int e = 0; e < 32; ++e) {
        Gh[dh + e][k] = hs[e];
        Gl[dh + e][k] = ls[e];
      }
    }
  }
  int w = tid >> 6, lane = tid & 63;
  int q = lane >> 4, l16 = lane & 15;
  int mh2 = w >> 1, nh = w & 1;
  float colsum[2] = {0.f, 0.f};
  f32x4 zf = {0.f, 0.f, 0.f, 0.f};
  for (int m0h = 0; m0h < 128; m0h += 64) {
    if (m0h >= lm) break;  // block-uniform
    // ---- stage P m-half: Ph[m][k] ----
    {
      int m = tid >> 2, ko = (tid & 3) * 32;
      if (ko < nkc * 32) {
        const uint4* sh = (const uint4*)(Pbh + (size_t)(m0h + m) * 128 + ko);
        const uint4* sl = (const uint4*)(Pbl + (size_t)(m0h + m) * 128 + ko);
#pragma unroll
        for (int i = 0; i < 4; ++i) {
          *(uint4*)&Ph[m][ko + 8 * i] = sh[i];
          *(uint4*)&Pl[m][ko + 8 * i] = sl[i];
        }
      }
    }
    __syncthreads();
    f32x4 acc[2][2];
#pragma unroll
    for (int s = 0; s < 2; ++s)
#pragma unroll
      for (int t = 0; t < 2; ++t) acc[s][t] = zf;
    for (int kc = 0; kc < nkc; ++kc) {
      int kw = kc * 32 + q * 8;
      bf16x8 ah0 = *(const bf16x8*)&Ph[mh2 * 32 + l16][kw];
      bf16x8 ah1 = *(const bf16x8*)&Ph[mh2 * 32 + 16 + l16][kw];
      bf16x8 al0 = *(const bf16x8*)&Pl[mh2 * 32 + l16][kw];
      bf16x8 al1 = *(const bf16x8*)&Pl[mh2 * 32 + 16 + l16][kw];
#pragma unroll
      for (int t = 0; t < 2; ++t) {
        int drow = nh * 32 + t * 16 + l16;
        bf16x8 bh = *(const bf16x8*)&Gh[drow][kw];
        bf16x8 bl = *(const bf16x8*)&Gl[drow][kw];
        acc[0][t] = __builtin_amdgcn_mfma_f32_16x16x32_bf16(ah0, bh, acc[0][t], 0, 0, 0);
        acc[0][t] = __builtin_amdgcn_mfma_f32_16x16x32_bf16(ah0, bl, acc[0][t], 0, 0, 0);
        acc[0][t] = __builtin_amdgcn_mfma_f32_16x16x32_bf16(al0, bh, acc[0][t], 0, 0, 0);
        acc[1][t] = __builtin_amdgcn_mfma_f32_16x16x32_bf16(ah1, bh, acc[1][t], 0, 0, 0);
        acc[1][t] = __builtin_amdgcn_mfma_f32_16x16x32_bf16(ah1, bl, acc[1][t], 0, 0, 0);
        acc[1][t] = __builtin_amdgcn_mfma_f32_16x16x32_bf16(al1, bh, acc[1][t], 0, 0, 0);
      }
    }
    // ---- epilogue: + Hc + bc, relu, column accumulate ----
#pragma unroll
    for (int t = 0; t < 2; ++t) {
      int col = d0 + nh * 32 + t * 16 + l16;
      if (col < HDIM) {
        float bcv = bc[col];
#pragma unroll
        for (int s = 0; s < 2; ++s) {
#pragma unroll
          for (int r = 0; r < 4; ++r) {
            int mi = m0h + mh2 * 32 + s * 16 + q * 4 + r;
            if (mi < lm) {
              float y = acc[s][t][r] + Hc[(size_t)imx[mi] * HDIM + col] + bcv;
              colsum[t] += y > 0.f ? y : 0.f;
            }
          }
        }
      }
    }
    __syncthreads();  // before re-staging Ph/Pl
  }
  // ---- reduce colsum across quads (shuffle) and waves (LDS) ----
#pragma unroll
  for (int t = 0; t < 2; ++t) {
    colsum[t] += __shfl_xor(colsum[t], 16, 64);
    colsum[t] += __shfl_xor(colsum[t], 32, 64);
  }
  if (lane < 16) {
    red[w * 32 + lane] = colsum[0];
    red[w * 32 + 16 + lane] = colsum[1];
  }
  __syncthreads();
  if (tid < 64) {
    int nh2 = tid >> 5, dj = tid & 31;
    float sv = red[nh2 * 32 + dj] + red[(2 + nh2) * 32 + dj];
    int col = d0 + nh2 * 32 + dj;
    if (col < HDIM) outacc[(size_t)b * HDIM + col] = sv;
  }
}

// ---------------- K8: classifier head -> out [B,2] -------------------------
__global__ __launch_bounds__(320) void k_cls(
    const float* __restrict__ cr, const float* __restrict__ cc,
    const float* __restrict__ Wcls, const float* __restrict__ bcls,
    const float* __restrict__ Wout, const float* __restrict__ bout,
    float* __restrict__ out) {
  __shared__ __align__(16) float cz[2 * HDIM];
  __shared__ float zz[HDIM];
  int b = blockIdx.x, tid = threadIdx.x;
  if (tid < HDIM) {
    cz[tid] = cr[(size_t)b * HDIM + tid];
    cz[HDIM + tid] = cc[(size_t)b * HDIM + tid];
  }
  __syncthreads();
  if (tid < HDIM) {
    float acc = bcls[tid];
    for (int k4 = 0; k4 < 2 * HDIM; k4 += 4) {
      float4 c = *(const float4*)&cz[k4];
      acc += c.x * Wcls[(size_t)(k4 + 0) * HDIM + tid] +
             c.y * Wcls[(size_t)(k4 + 1) * HDIM + tid] +
             c.z * Wcls[(size_t)(k4 + 2) * HDIM + tid] +
             c.w * Wcls[(size_t)(k4 + 3) * HDIM + tid];
    }
    zz[tid] = acc > 0.f ? acc : 0.f;
  }
  __syncthreads();
  int o = tid >> 6, lane = tid & 63;
  if (o < 2) {
    float p = 0.f;
    for (int j = lane; j < HDIM; j += 64) p += zz[j] * Wout[(size_t)j * 2 + o];
#pragma unroll
    for (int off = 32; off > 0; off >>= 1) p += __shfl_down(p, off, 64);
    if (lane == 0) out[b * 2 + o] = p + bout[o];
  }
}

extern "C" void kernel_launch(void* const* d_in, const int* in_sizes, int n_in,
                              void* d_out, int out_size, void* d_ws, size_t ws_size,
                              hipStream_t stream) {
  (void)in_sizes; (void)n_in; (void)out_size; (void)ws_size;
  const int* data = (const int*)d_in[0];
  const int* row_idx = (const int*)d_in[1];
  const int* col_idx = (const int*)d_in[2];
  const int* row_len = (const int*)d_in[3];
  const int* col_len = (const int*)d_in[4];
  const float* emb = (const float*)d_in[5];
  const float* W1 = (const float*)d_in[6];
  const float* b1 = (const float*)d_in[7];
  const float* W2 = (const float*)d_in[8];
  const float* b2 = (const float*)d_in[9];
  const float* Wc = (const float*)d_in[10];
  const float* bc = (const float*)d_in[11];
  const float* Wcls = (const float*)d_in[12];
  const float* bcls = (const float*)d_in[13];
  const float* Wout = (const float*)d_in[14];
  const float* bout = (const float*)d_in[15];
  float* out = (float*)d_out;

  char* wp = (char*)d_ws;
  auto carve = [&](size_t bytes) {
    char* p = wp; wp += (bytes + 255) & ~(size_t)255; return p;
  };
  ushort* enchi = (ushort*)carve((size_t)NS * KPAD * 2);
  ushort* enclo = (ushort*)carve((size_t)NS * KPAD * 2);
  ushort* h1hi = (ushort*)carve((size_t)NS * KPAD * 2);
  ushort* h1lo = (ushort*)carve((size_t)NS * KPAD * 2);
  ushort* hehi = (ushort*)carve((size_t)NS * KPAD * 2);
  ushort* helo = (ushort*)carve((size_t)NS * KPAD * 2);
  ushort* W1hi = (ushort*)carve((size_t)NPADW * KPAD * 2);
  ushort* W1lo = (ushort*)carve((size_t)NPADW * KPAD * 2);
  ushort* W2hi = (ushort*)carve((size_t)NPADW * KPAD * 2);
  ushort* W2lo = (ushort*)carve((size_t)NPADW * KPAD * 2);
  ushort* Wchi = (ushort*)carve((size_t)640 * KPAD * 2);
  ushort* Wclo = (ushort*)carve((size_t)640 * KPAD * 2);
  float* Hc = (float*)carve((size_t)NS * HDIM * 4);
  ushort* Hcbhi = (ushort*)carve((size_t)NS * KPAD * 2);
  ushort* Hcblo = (ushort*)carve((size_t)NS * KPAD * 2);
  float* Km = (float*)carve((size_t)BB * NMAX * MMAX * 4);
  ushort* Phi = (ushort*)carve((size_t)BB * 128 * 128 * 2);
  ushort* Plo = (ushort*)carve((size_t)BB * 128 * 128 * 2);
  ushort* PThi = (ushort*)carve((size_t)BB * 128 * 128 * 2);
  ushort* PTlo = (ushort*)carve((size_t)BB * 128 * 128 * 2);
  float* cr = (float*)carve((size_t)BB * HDIM * 4);
  float* cc = (float*)carve((size_t)BB * HDIM * 4);
  // hn planes reuse h1 planes (h1 dead after GEMM2; norm_split runs after)
  ushort* hnhi = h1hi;
  ushort* hnlo = h1lo;

  int gM = (NS + 63) / 64;  // 157
  int cvtTotal = 2 * NPADW * KPAD + 640 * KPAD;

  k_embed<<<NS, 256, 0, stream>>>(data, emb, enchi, enclo);
  k_cvt_all<<<(cvtTotal + 255) / 256, 256, 0, stream>>>(
      W1, W2, Wc, W1hi, W1lo, W2hi, W2lo, Wchi, Wclo);
  k_gemm_mfma<<<dim3(gM, 3), 256, 0, stream>>>(
      enchi, enclo, W1hi, W1lo, b1, NS, HDIM, 1, nullptr, 0, h1hi, h1lo, 0);
  k_gemm_mfma<<<dim3(gM, 3), 256, 0, stream>>>(
      h1hi, h1lo, W2hi, W2lo, b2, NS, HDIM, 1, nullptr, 0, hehi, helo, 0);
  k_norm_split<<<(NS + 3) / 4, 256, 0, stream>>>(hehi, helo, hnhi, hnlo);
  k_gemm_mfma<<<dim3(gM, 5), 256, 0, stream>>>(
      hehi, helo, Wchi, Wclo, nullptr, NS, 2 * HDIM, 0, Hc, HDIM, Hcbhi,
      Hcblo, 300);
  k_cost_mfma<<<dim3(2, 2, BB), 256, 0, stream>>>(hnhi, hnlo, row_idx, col_idx,
                                                  row_len, col_len, Km);
  k_sinkhorn<<<BB, 512, 0, stream>>>(Km, row_len, col_len, Phi, Plo, PThi,
                                     PTlo);
  k_att_mfma<<<dim3(5, BB, 2), 256, 0, stream>>>(
      Phi, Plo, PThi, PTlo, Hc, Hcbhi, Hcblo, row_idx, col_idx, row_len,
      col_len, bc, cr, cc);
  k_cls<<<BB, 320, 0, stream>>>(cr, cc, Wcls, bcls, Wout, bout, out);
}